// Round 2
// baseline (427.065 us; speedup 1.0000x reference)
//
#include <hip/hip_runtime.h>
#include <math.h>

#define NB 64
#define NT 512
#define ND 768
#define NK 29
#define L2E 1.4426950408889634f
#define LN2 0.6931471805599453f
#define NEG_BIG -1e30f

// ---------------------------------------------------------------------------
// Kernel 1: emissions  em[tok][k] = dot(emb[x[tok]], w[k]) + b[k]
// 1024 blocks x 128 threads = 2048 waves. wave = (64 tokens, k-quarter).
// e rows staged per-wave in LDS [64][68] tile-by-tile (coalesced global,
// in-wave DS ordering => no barriers), then cached in 16 VGPRs per tile.
// w accessed with wave-uniform addresses => scalar (SGPR) loads.
// Inner accumulate expression/order is bit-identical to R1 per (token,k).
// ---------------------------------------------------------------------------
template<int KN>
__device__ __forceinline__ void emis_wave(
    const int* __restrict__ x, const float* __restrict__ emb,
    const float* __restrict__ w, const float* __restrict__ bias,
    float* __restrict__ em, float* eb, int tokbase, int kbase, int lane)
{
    const int tok = tokbase + lane;
    const int srow = lane >> 3;        // staging: 8 lanes per row
    const int soff = (lane & 7) * 4;   // float offset 0..28

    const float* sp[8];
#pragma unroll
    for (int i = 0; i < 8; ++i)
        sp[i] = emb + (size_t)x[tokbase + srow + 8 * i] * ND + soff;

    float acc[KN];
#pragma unroll
    for (int k = 0; k < KN; ++k) acc[k] = 0.f;

    const float* myrow = eb + lane * 68;

    for (int tile = 0; tile < 12; ++tile) {
        // stage 64 rows x 64 floats (coalesced: 8 rows x 2 lines per instr)
#pragma unroll
        for (int i = 0; i < 8; ++i) {
            float4 v0 = *(const float4*)(sp[i] + tile * 64);
            float4 v1 = *(const float4*)(sp[i] + tile * 64 + 32);
            int r = srow + 8 * i;
            *(float4*)(eb + r * 68 + soff) = v0;
            *(float4*)(eb + r * 68 + 32 + soff) = v1;
        }
        // in-wave DS ordering: reads below see the writes above (single wave)
        float4 ereg[16];
#pragma unroll
        for (int c = 0; c < 16; ++c) ereg[c] = *(const float4*)(myrow + c * 4);

#pragma unroll
        for (int k = 0; k < KN; ++k) {
            const float* wr = w + (size_t)(kbase + k) * ND + tile * 64;  // uniform
#pragma unroll
            for (int c = 0; c < 16; ++c) {
                float4 w4 = *(const float4*)(wr + c * 4);
                acc[k] += ereg[c].x * w4.x + ereg[c].y * w4.y
                        + ereg[c].z * w4.z + ereg[c].w * w4.w;
            }
        }
    }
#pragma unroll
    for (int k = 0; k < KN; ++k)
        em[(size_t)tok * NK + kbase + k] = acc[k] + bias[kbase + k];
}

__global__ __launch_bounds__(128) void k_emissions(
    const int* __restrict__ x, const float* __restrict__ emb,
    const float* __restrict__ w, const float* __restrict__ bias,
    float* __restrict__ em)
{
    __shared__ __align__(16) float elds[2][64 * 68];   // 34816 B
    const int wv = threadIdx.x >> 6;
    const int lane = threadIdx.x & 63;
    const int wave_id = blockIdx.x * 2 + wv;           // 0..2047
    const int q = wave_id & 3;
    const int tokbase = (wave_id >> 2) * 64;
    const int kbase = q * 8;
    if (q == 3) emis_wave<5>(x, emb, w, bias, em, elds[wv], tokbase, kbase, lane);
    else        emis_wave<8>(x, emb, w, bias, em, elds[wv], tokbase, kbase, lane);
}

// ---------------------------------------------------------------------------
// Kernel 2: scans. blocks 0..63 CRF forward, 64..127 Viterbi. 64 thr = 1 wave
// => no __syncthreads anywhere (in-order DS per wave).
// CRF: scaled exp-domain recurrence a_t = exp(em_t) .* (E^T a_{t-1}) with
// E = exp(trans); power-of-2 rescale every 16 steps. em staged in LDS.
// Viterbi: bit-identical arithmetic to R1; em prefetch distance-4.
// ---------------------------------------------------------------------------
__global__ __launch_bounds__(64) void k_scan(
    const float* __restrict__ em, const int* __restrict__ tags,
    const float* __restrict__ st, const float* __restrict__ en,
    const float* __restrict__ tr, float* __restrict__ part,
    float* __restrict__ out)
{
    __shared__ __align__(16) unsigned char smem[128 + NT * NK * 4];
    float* sA = (float*)smem;                          // 32 floats
    const float4* sA4 = (const float4*)smem;

    const int lane = threadIdx.x;

    if (blockIdx.x < NB) {
        // ----------------- CRF forward (scaled exp domain) -----------------
        const int b = blockIdx.x;
        const int jc = lane < NK ? lane : NK - 1;
        float* emS = (float*)(smem + 128);             // [512][29]
        {   // stage em slab: 14848 floats
            const float4* src = (const float4*)(em + (size_t)b * NT * NK);
            float4* dst = (float4*)emS;
            for (int i = lane; i < NT * NK / 4; i += 64) dst[i] = src[i];
        }
        float4 EC[8];
#pragma unroll
        for (int c4 = 0; c4 < 8; ++c4) {
            int i0 = c4 * 4;
            EC[c4].x = (i0 + 0 < NK) ? __expf(tr[(i0 + 0) * NK + jc]) : 0.f;
            EC[c4].y = (i0 + 1 < NK) ? __expf(tr[(i0 + 1) * NK + jc]) : 0.f;
            EC[c4].z = (i0 + 2 < NK) ? __expf(tr[(i0 + 2) * NK + jc]) : 0.f;
            EC[c4].w = (i0 + 3 < NK) ? __expf(tr[(i0 + 3) * NK + jc]) : 0.f;
        }
        // init (reads staged LDS: same wave, in-order)
        float a0v = __expf(st[jc] + emS[jc]);
        if (lane < 32) sA[lane] = (lane < NK) ? a0v : 0.f;

        int eshift = 0;
        float eemc = exp2f(emS[1 * NK + jc] * L2E);    // eem(t=1)
        float rawn = emS[2 * NK + jc];                 // raw(t=2)
        float anew = a0v;

        for (int t = 1; t < NT; ++t) {
            float4 A[8];
#pragma unroll
            for (int i = 0; i < 8; ++i) A[i] = sA4[i];
            float p0 = 0.f, p1 = 0.f, p2 = 0.f, p3 = 0.f;
#pragma unroll
            for (int i = 0; i < 8; ++i) {
                p0 = fmaf(A[i].x, EC[i].x, p0);
                p1 = fmaf(A[i].y, EC[i].y, p1);
                p2 = fmaf(A[i].z, EC[i].z, p2);
                p3 = fmaf(A[i].w, EC[i].w, p3);
            }
            anew = ((p0 + p1) + (p2 + p3)) * eemc;
            // refill eem pipeline (off critical chain)
            eemc = exp2f(rawn * L2E);
            int tn = t + 2; tn = tn < NT ? tn : NT - 1;
            rawn = emS[tn * NK + jc];

            if ((t & 15) == 0) {                       // adaptive pow2 rescale
                float m = anew;
#pragma unroll
                for (int s = 32; s; s >>= 1) m = fmaxf(m, __shfl_xor(m, s));
                int ex = ((__float_as_int(m) >> 23) & 255) - 127;
                anew *= __int_as_float((127 - ex) << 23);
                eshift += ex;
            }
            if (lane < 32) sA[lane] = (lane < NK) ? anew : 0.f;
        }
        // logZ = log(sum a * exp(en)) + eshift*ln2
        float val = (lane < NK) ? anew * __expf(en[jc]) : 0.f;
#pragma unroll
        for (int s = 32; s; s >>= 1) val += __shfl_xor(val, s);
        float logZ = logf(val) + (float)eshift * LN2;
        // numerator (exact, matches R1)
        const int* tg = tags + b * NT;
        float p = 0.f;
        for (int t = lane; t < NT; t += 64) {
            int tt = tg[t];
            p += emS[t * NK + tt];
            if (t == 0) p += st[tt];
            else        p += tr[tg[t - 1] * NK + tt];
            if (t == NT - 1) p += en[tt];
        }
#pragma unroll
        for (int s = 32; s; s >>= 1) p += __shfl_xor(p, s);
        if (lane == 0) part[b] = logZ - p;
    } else {
        // ----------------- Viterbi + backtrace (bit-identical to R1) -------
        const int b = blockIdx.x - NB;
        const float* emb_b = em + (size_t)b * NT * NK;
        unsigned char* sbp = smem + 128;               // [511][32]
        unsigned char* spath = smem + 128 + 511 * 32;  // [512]

        const int j = lane & 31;
        const int h = lane >> 5;
        const bool jact = (j < NK);
        const int jc = jact ? j : NK - 1;

        float4 Tq[4];
#pragma unroll
        for (int c4 = 0; c4 < 4; ++c4) {
            int i0 = h * 16 + c4 * 4;
            Tq[c4].x = (i0 + 0 < NK) ? tr[(i0 + 0) * NK + jc] : 0.f;
            Tq[c4].y = (i0 + 1 < NK) ? tr[(i0 + 1) * NK + jc] : 0.f;
            Tq[c4].z = (i0 + 2 < NK) ? tr[(i0 + 2) * NK + jc] : 0.f;
            Tq[c4].w = (i0 + 3 < NK) ? tr[(i0 + 3) * NK + jc] : 0.f;
        }
        float sc = jact ? (st[jc] + emb_b[jc]) : NEG_BIG;

        float e0 = emb_b[1 * NK + jc];
        float e1 = emb_b[2 * NK + jc];
        float e2 = emb_b[3 * NK + jc];
        float e3 = emb_b[4 * NK + jc];

        auto vstep = [&](int t, float emt) {
            if (h == 0) sA[j] = sc;
            float4 a0 = sA4[h * 4 + 0], a1 = sA4[h * 4 + 1];
            float4 a2 = sA4[h * 4 + 2], a3 = sA4[h * 4 + 3];
            float vv[16];
            vv[0] = a0.x + Tq[0].x;  vv[1] = a0.y + Tq[0].y;
            vv[2] = a0.z + Tq[0].z;  vv[3] = a0.w + Tq[0].w;
            vv[4] = a1.x + Tq[1].x;  vv[5] = a1.y + Tq[1].y;
            vv[6] = a1.z + Tq[1].z;  vv[7] = a1.w + Tq[1].w;
            vv[8] = a2.x + Tq[2].x;  vv[9] = a2.y + Tq[2].y;
            vv[10] = a2.z + Tq[2].z; vv[11] = a2.w + Tq[2].w;
            vv[12] = a3.x + Tq[3].x; vv[13] = a3.y + Tq[3].y;
            vv[14] = a3.z + Tq[3].z; vv[15] = a3.w + Tq[3].w;
            float m8[8], m4[4];
#pragma unroll
            for (int i = 0; i < 8; ++i) m8[i] = fmaxf(vv[i], vv[i + 8]);
#pragma unroll
            for (int i = 0; i < 4; ++i) m4[i] = fmaxf(m8[i], m8[i + 4]);
            float best = fmaxf(fmaxf(m4[0], m4[1]), fmaxf(m4[2], m4[3]));
            unsigned msk = 0;
#pragma unroll
            for (int i = 0; i < 16; ++i) msk |= (vv[i] == best) ? (1u << i) : 0u;
            int bi = h * 16 + __builtin_ctz(msk);      // first max in half
            float ob = __shfl_xor(best, 32);
            int   oi = __shfl_xor(bi, 32);
            float bl = h ? ob : best; int il = h ? oi : bi;   // low-i half
            float bh = h ? best : ob; int ih = h ? bi : oi;   // high-i half
            float fb = (bh > bl) ? bh : bl;                   // ties -> lower i
            int   fi = (bh > bl) ? ih : il;
            if (h == 0) sbp[(t - 1) * 32 + j] = (unsigned char)fi;
            sc = jact ? (fb + emt) : NEG_BIG;
        };

        int t = 1;
        for (; t + 3 < NT; t += 4) {                   // t = 1..508
            vstep(t + 0, e0); { int tn = t + 4; tn = tn < NT ? tn : NT - 1; e0 = emb_b[tn * NK + jc]; }
            vstep(t + 1, e1); { int tn = t + 5; tn = tn < NT ? tn : NT - 1; e1 = emb_b[tn * NK + jc]; }
            vstep(t + 2, e2); { int tn = t + 6; tn = tn < NT ? tn : NT - 1; e2 = emb_b[tn * NK + jc]; }
            vstep(t + 3, e3); { int tn = t + 7; tn = tn < NT ? tn : NT - 1; e3 = emb_b[tn * NK + jc]; }
        }
        vstep(509, e0); vstep(510, e1); vstep(511, e2);

        float v = jact ? (sc + en[jc]) : NEG_BIG;
        float M = v;
#pragma unroll
        for (int s = 32; s; s >>= 1) M = fmaxf(M, __shfl_xor(M, s));
        unsigned long long mk = __ballot(jact && h == 0 && v == M);
        int last = (int)__builtin_ctzll(mk);
        if (lane == 0) {
            int cur = last;
            spath[NT - 1] = (unsigned char)cur;
            for (int tt = NT - 1; tt >= 1; --tt) {
                cur = sbp[(tt - 1) * 32 + cur];
                spath[tt - 1] = (unsigned char)cur;
            }
        }
        // in-wave DS ordering: lane-0 writes visible to all lanes below
        float* op = out + 1 + (size_t)b * NT;
        for (int tt = lane; tt < NT; tt += 64) op[tt] = (float)spath[tt];
    }
}

// ---------------------------------------------------------------------------
// Kernel 3: nll = sum_b (logZ_b - num_b)
// ---------------------------------------------------------------------------
__global__ __launch_bounds__(64) void k_finish(const float* __restrict__ part,
                                               float* __restrict__ out)
{
    float v = part[threadIdx.x];
#pragma unroll
    for (int s = 32; s; s >>= 1) v += __shfl_xor(v, s);
    if (threadIdx.x == 0) out[0] = v;
}

extern "C" void kernel_launch(void* const* d_in, const int* in_sizes, int n_in,
                              void* d_out, int out_size, void* d_ws, size_t ws_size,
                              hipStream_t stream) {
    const int*   x    = (const int*)d_in[0];
    const int*   tags = (const int*)d_in[1];
    const float* emb  = (const float*)d_in[2];
    const float* w    = (const float*)d_in[3];
    const float* bias = (const float*)d_in[4];
    const float* st   = (const float*)d_in[5];
    const float* en   = (const float*)d_in[6];
    const float* tr   = (const float*)d_in[7];
    float* out = (float*)d_out;

    float* em   = (float*)d_ws;                                     // B*T*K
    float* part = (float*)((char*)d_ws + (size_t)NB * NT * NK * 4); // B floats

    k_emissions<<<1024, 128, 0, stream>>>(x, emb, w, bias, em);
    k_scan<<<2 * NB, 64, 0, stream>>>(em, tags, st, en, tr, part, out);
    k_finish<<<1, 64, 0, stream>>>(part, out);
}